// Round 1
// baseline (15428.387 us; speedup 1.0000x reference)
//
#include <hip/hip_runtime.h>
#include <math.h>

// Problem constants
#define B_ 4
#define T_ 10
#define H_ 144
#define W_ 256
#define C_ 3
#define F_ 64

static __device__ __forceinline__ float hs(float x) {
    return fminf(fmaxf(fmaf(x, 0.2f, 0.5f), 0.f), 1.f);
}

// -------- weight repack: Wh [25][64][256] -> [25][64][64][4] (c, f, gate) --------
__global__ void repack_wh(const float* __restrict__ w, float* __restrict__ o) {
    int i = blockIdx.x * 256 + threadIdx.x;
    if (i >= 25 * 64 * 256) return;
    int g = i % 256;
    int c = (i / 256) % 64;
    int kk = i / (256 * 64);
    int gate = g / 64, f = g % 64;
    o[((kk * 64 + c) * 64 + f) * 4 + gate] = w[i];
}

// Wx [25][3][256] -> [25][3][64][4]
__global__ void repack_wx(const float* __restrict__ w, float* __restrict__ o) {
    int i = blockIdx.x * 256 + threadIdx.x;
    if (i >= 25 * 3 * 256) return;
    int g = i % 256;
    int c = (i / 256) % 3;
    int kk = i / (256 * 3);
    int gate = g / 64, f = g % 64;
    o[((kk * 3 + c) * 64 + f) * 4 + gate] = w[i];
}

// -------- fused ConvLSTM step --------
// grid: (W/32, H, B), block: 256 = 64 f-lanes x 4 pixel-groups, 8 px/thread
#define LTW 32
__global__ __launch_bounds__(256) void lstm_step(
    const float* __restrict__ x,    // [B,T,H,W,3]
    const float* __restrict__ wxr,  // [25][3][64][4]
    const float* __restrict__ whr,  // [25][64][64][4]
    const float* __restrict__ bias, // [256] gate-major (i,f,c,o)
    const float* __restrict__ h_prev,
    float* __restrict__ h_out,
    float* __restrict__ c_io,
    int t, int first)
{
    __shared__ float sh[5][LTW + 4][64];
    __shared__ float sx[5][LTW + 4][3];

    const int b = blockIdx.z, y = blockIdx.y, x0 = blockIdx.x * LTW;
    const int tid = threadIdx.x;

    // stage h tile (skip if h==0 at t=0)
    if (!first) {
        for (int e = tid; e < 5 * (LTW + 4) * 64; e += 256) {
            int r = e / ((LTW + 4) * 64);
            int rem = e % ((LTW + 4) * 64);
            int cc = rem / 64, ch = rem % 64;
            int yg = y + r - 2, xg = x0 + cc - 2;
            float v = 0.f;
            if (yg >= 0 && yg < H_ && xg >= 0 && xg < W_)
                v = h_prev[((b * H_ + yg) * W_ + xg) * 64 + ch];
            sh[r][cc][ch] = v;
        }
    }
    // stage x tile
    for (int e = tid; e < 5 * (LTW + 4) * 3; e += 256) {
        int r = e / ((LTW + 4) * 3);
        int rem = e % ((LTW + 4) * 3);
        int cc = rem / 3, ci = rem % 3;
        int yg = y + r - 2, xg = x0 + cc - 2;
        float v = 0.f;
        if (yg >= 0 && yg < H_ && xg >= 0 && xg < W_)
            v = x[(((b * T_ + t) * H_ + yg) * W_ + xg) * 3 + ci];
        sx[r][cc][ci] = v;
    }
    __syncthreads();

    const int f = tid & 63;
    const int pg = tid >> 6;
    const int p0 = pg * 8;

    float acc[8][4];
#pragma unroll
    for (int p = 0; p < 8; ++p)
#pragma unroll
        for (int g = 0; g < 4; ++g) acc[p][g] = 0.f;

    // x-conv contribution
    for (int ky = 0; ky < 5; ++ky) {
#pragma unroll
        for (int kx = 0; kx < 5; ++kx) {
            const float* wp = &wxr[(((ky * 5 + kx) * 3) * 64 + f) * 4];
            const float* sp = &sx[ky][p0 + kx][0];
#pragma unroll
            for (int ci = 0; ci < 3; ++ci) {
                float4 w = *(const float4*)(wp + ci * 256);
#pragma unroll
                for (int p = 0; p < 8; ++p) {
                    float xv = sp[p * 3 + ci];
                    acc[p][0] = fmaf(xv, w.x, acc[p][0]);
                    acc[p][1] = fmaf(xv, w.y, acc[p][1]);
                    acc[p][2] = fmaf(xv, w.z, acc[p][2]);
                    acc[p][3] = fmaf(xv, w.w, acc[p][3]);
                }
            }
        }
    }

    // h-conv contribution
    if (!first) {
        for (int ky = 0; ky < 5; ++ky) {
#pragma unroll
            for (int kx = 0; kx < 5; ++kx) {
                const float* wp = &whr[(((ky * 5 + kx) * 64) * 64 + f) * 4];
                const float* sp = &sh[ky][p0 + kx][0];
                for (int c = 0; c < 64; ++c) {
                    float4 w = *(const float4*)(wp + c * 256);
#pragma unroll
                    for (int p = 0; p < 8; ++p) {
                        float hv = sp[p * 64 + c];
                        acc[p][0] = fmaf(hv, w.x, acc[p][0]);
                        acc[p][1] = fmaf(hv, w.y, acc[p][1]);
                        acc[p][2] = fmaf(hv, w.z, acc[p][2]);
                        acc[p][3] = fmaf(hv, w.w, acc[p][3]);
                    }
                }
            }
        }
    }

    const float b0 = bias[f], b1 = bias[64 + f], b2 = bias[128 + f], b3 = bias[192 + f];

#pragma unroll
    for (int p = 0; p < 8; ++p) {
        int xx = x0 + p0 + p;
        long idx = ((long)(b * H_ + y) * W_ + xx) * 64 + f;
        float zi = acc[p][0] + b0;
        float zf = acc[p][1] + b1;
        float zc = acc[p][2] + b2;
        float zo = acc[p][3] + b3;
        float ig = hs(zi), fg = hs(zf), og = hs(zo);
        float cp = first ? 0.f : c_io[idx];
        float cn = fg * cp + ig * tanhf(zc);
        float hn = og * tanhf(cn);
        c_io[idx] = cn;
        h_out[idx] = hn;
    }
}

// -------- BatchNorm (inference) --------
__global__ void bn_k(const float* __restrict__ in, float* __restrict__ out,
                     const float* __restrict__ gamma, const float* __restrict__ beta,
                     const float* __restrict__ mean, const float* __restrict__ var, int n) {
    for (int i = blockIdx.x * blockDim.x + threadIdx.x; i < n; i += gridDim.x * blockDim.x) {
        int c = i & 63;
        float s = rsqrtf(var[c] + 1e-3f) * gamma[c];
        out[i] = (in[i] - mean[c]) * s + beta[c];
    }
}

// -------- generic direct conv, LDS-tiled, ReLU --------
template <int KH, int KW, int CIN, int COUT, int CC, int TW>
__global__ __launch_bounds__(256) void conv2d_k(
    const float* __restrict__ in, const float* __restrict__ wgt,
    const float* __restrict__ bias, float* __restrict__ out)
{
    constexpr int PG = 256 / COUT;
    constexpr int PXT = TW / PG;
    constexpr int TC = TW + KW - 1;
    constexpr int PADX = KW / 2, PADY = KH / 2;
    __shared__ float s[KH][TC][CC + 1];

    const int b = blockIdx.z, y = blockIdx.y, x0 = blockIdx.x * TW;
    const int tid = threadIdx.x;
    const int cout = tid % COUT;
    const int pg = tid / COUT;
    const int p0 = pg * PXT;

    float acc[PXT];
#pragma unroll
    for (int p = 0; p < PXT; ++p) acc[p] = 0.f;

    for (int c0 = 0; c0 < CIN; c0 += CC) {
        __syncthreads();
        for (int e = tid; e < KH * TC * CC; e += 256) {
            int r = e / (TC * CC);
            int rem = e % (TC * CC);
            int cc = rem / CC, ch = rem % CC;
            int yg = y + r - PADY, xg = x0 + cc - PADX;
            float v = 0.f;
            if (yg >= 0 && yg < H_ && xg >= 0 && xg < W_)
                v = in[((b * H_ + yg) * W_ + xg) * CIN + c0 + ch];
            s[r][cc][ch] = v;
        }
        __syncthreads();
        for (int ky = 0; ky < KH; ++ky) {
#pragma unroll
            for (int kx = 0; kx < KW; ++kx) {
                for (int c = 0; c < CC; ++c) {
                    float w = wgt[(((ky * KW + kx) * CIN) + c0 + c) * COUT + cout];
#pragma unroll
                    for (int p = 0; p < PXT; ++p)
                        acc[p] = fmaf(s[ky][p0 + p + kx][c], w, acc[p]);
                }
            }
        }
    }

    float bv = bias[cout];
#pragma unroll
    for (int p = 0; p < PXT; ++p) {
        float v = fmaxf(acc[p] + bv, 0.f);
        out[((b * H_ + y) * W_ + x0 + p0 + p) * COUT + cout] = v;
    }
}

// -------- conv5: 3x3, 64 -> 3, sigmoid --------
__global__ __launch_bounds__(256) void conv5_k(
    const float* __restrict__ in, const float* __restrict__ wgt,
    const float* __restrict__ bias, float* __restrict__ out)
{
    constexpr int CC = 16;
    __shared__ float s[3][W_ + 2][CC + 1];
    const int b = blockIdx.z, y = blockIdx.y;
    const int tid = threadIdx.x; // = pixel x

    float acc[3] = {0.f, 0.f, 0.f};
    for (int c0 = 0; c0 < 64; c0 += CC) {
        __syncthreads();
        for (int e = tid; e < 3 * (W_ + 2) * CC; e += 256) {
            int r = e / ((W_ + 2) * CC);
            int rem = e % ((W_ + 2) * CC);
            int cc = rem / CC, ch = rem % CC;
            int yg = y + r - 1, xg = cc - 1;
            float v = 0.f;
            if (yg >= 0 && yg < H_ && xg >= 0 && xg < W_)
                v = in[((b * H_ + yg) * W_ + xg) * 64 + c0 + ch];
            s[r][cc][ch] = v;
        }
        __syncthreads();
        for (int ky = 0; ky < 3; ++ky) {
#pragma unroll
            for (int kx = 0; kx < 3; ++kx) {
                for (int c = 0; c < CC; ++c) {
                    const float* wp = &wgt[((ky * 3 + kx) * 64 + c0 + c) * 3];
                    float v = s[ky][tid + kx][c];
                    acc[0] = fmaf(v, wp[0], acc[0]);
                    acc[1] = fmaf(v, wp[1], acc[1]);
                    acc[2] = fmaf(v, wp[2], acc[2]);
                }
            }
        }
    }
#pragma unroll
    for (int j = 0; j < 3; ++j) {
        float v = acc[j] + bias[j];
        v = 1.f / (1.f + expf(-v));
        out[((b * H_ + y) * W_ + tid) * 3 + j] = v;
    }
}

extern "C" void kernel_launch(void* const* d_in, const int* in_sizes, int n_in,
                              void* d_out, int out_size, void* d_ws, size_t ws_size,
                              hipStream_t stream) {
    const float* x     = (const float*)d_in[0];
    const float* Wx    = (const float*)d_in[1];
    const float* Wh    = (const float*)d_in[2];
    const float* bl    = (const float*)d_in[3];
    const float* gamma = (const float*)d_in[4];
    const float* beta  = (const float*)d_in[5];
    const float* mmean = (const float*)d_in[6];
    const float* mvar  = (const float*)d_in[7];
    const float* W1 = (const float*)d_in[8];
    const float* b1 = (const float*)d_in[9];
    const float* W2 = (const float*)d_in[10];
    const float* b2 = (const float*)d_in[11];
    const float* W3 = (const float*)d_in[12];
    const float* b3 = (const float*)d_in[13];
    const float* W4 = (const float*)d_in[14];
    const float* b4 = (const float*)d_in[15];
    const float* W5 = (const float*)d_in[16];
    const float* b5 = (const float*)d_in[17];
    float* out = (float*)d_out;

    const long NHWF = (long)B_ * H_ * W_ * 64;
    float* hA  = (float*)d_ws;
    float* hB  = hA + NHWF;
    float* cb  = hB + NHWF;
    float* whr = cb + NHWF;
    float* wxr = whr + 25 * 64 * 256;

    repack_wh<<<(25 * 64 * 256 + 255) / 256, 256, 0, stream>>>(Wh, whr);
    repack_wx<<<(25 * 3 * 256 + 255) / 256, 256, 0, stream>>>(Wx, wxr);

    dim3 lgrid(W_ / LTW, H_, B_);
    for (int t = 0; t < T_; ++t) {
        const float* hp = (t & 1) ? hA : hB;   // previous step's output
        float* ho = (t & 1) ? hB : hA;
        lstm_step<<<lgrid, 256, 0, stream>>>(x, wxr, whr, bl, hp, ho, cb, t, t == 0 ? 1 : 0);
    }
    // final h in hB (t=9)

    bn_k<<<2048, 256, 0, stream>>>(hB, cb, gamma, beta, mmean, mvar, (int)NHWF);

    conv2d_k<9, 9, 64, 16, 16, 64><<<dim3(W_ / 64, H_, B_), 256, 0, stream>>>(cb, W1, b1, hB);
    conv2d_k<5, 5, 16, 32, 16, 32><<<dim3(W_ / 32, H_, B_), 256, 0, stream>>>(hB, W2, b2, hA);
    conv2d_k<3, 3, 32, 64, 32, 16><<<dim3(W_ / 16, H_, B_), 256, 0, stream>>>(hA, W3, b3, hB);
    conv2d_k<3, 3, 64, 64, 32, 16><<<dim3(W_ / 16, H_, B_), 256, 0, stream>>>(hB, W4, b4, hA);
    conv5_k<<<dim3(1, H_, B_), 256, 0, stream>>>(hA, W5, b5, out);
}

// Round 2
// 3068.312 us; speedup vs baseline: 5.0283x; 5.0283x over previous
//
#include <hip/hip_runtime.h>
#include <math.h>

#define B_ 4
#define T_ 10
#define H_ 144
#define W_ 256
#define F_ 64

typedef __attribute__((ext_vector_type(8))) __bf16 bf16x8;
typedef __attribute__((ext_vector_type(4))) float f32x4;

static __device__ __forceinline__ float hs_(float x) {
    return fminf(fmaxf(fmaf(x, 0.2f, 0.5f), 0.f), 1.f);
}
static __device__ __forceinline__ unsigned short f2bf(float f) {
    unsigned u = __builtin_bit_cast(unsigned, f);
    u += 0x7fff + ((u >> 16) & 1);
    return (unsigned short)(u >> 16);
}
static __device__ __forceinline__ float bf2f(unsigned short s) {
    unsigned u = ((unsigned)s) << 16;
    return __builtin_bit_cast(float, u);
}

// ---- repack Wh [5][5][64][256] -> [25][2][4 gate][4 wf][64 lane][8] bf16 ----
__global__ void repack_wh_mfma(const float* __restrict__ w, unsigned short* __restrict__ o) {
    int idx = blockIdx.x * 256 + threadIdx.x;
    if (idx >= 25 * 2 * 4 * 4 * 64) return;
    int l = idx & 63;
    int wf = (idx >> 6) & 3;
    int g = (idx >> 8) & 3;
    int ch = (idx >> 10) & 1;
    int tap = idx >> 11;
    int n = g * 64 + wf * 16 + (l & 15);
    unsigned short* dst = o + (size_t)idx * 8;
#pragma unroll
    for (int j = 0; j < 8; ++j) {
        int c = ch * 32 + (l >> 4) * 8 + j;
        dst[j] = f2bf(w[((size_t)(tap * 64 + c)) * 256 + n]);
    }
}

// ---- repack Wx [5][5][3][256] -> [5 ky][4 gate][4 wf][64 lane][8] bf16 (k=kx*3+c, 15 real + pad) ----
__global__ void repack_wx_mfma(const float* __restrict__ w, unsigned short* __restrict__ o) {
    int idx = blockIdx.x * 256 + threadIdx.x;
    if (idx >= 5 * 4 * 4 * 64) return;
    int l = idx & 63;
    int wf = (idx >> 6) & 3;
    int g = (idx >> 8) & 3;
    int ky = idx >> 10;
    int n = g * 64 + wf * 16 + (l & 15);
    unsigned short* dst = o + (size_t)idx * 8;
#pragma unroll
    for (int j = 0; j < 8; ++j) {
        int k = (l >> 4) * 8 + j;
        unsigned short v = 0;
        if (k < 15) {
            int kx = k / 3, c = k - kx * 3;
            v = f2bf(w[((size_t)((ky * 5 + kx) * 3 + c)) * 256 + n]);
        }
        dst[j] = v;
    }
}

// ---- fused ConvLSTM step via bf16 MFMA ----
// grid (W/64, H, B), block 256 = 4 waves; wave w: 64 px x (f in [16w,16w+16)) x all 4 gates
#define MT 64
__global__ __launch_bounds__(256) void lstm_mfma(
    const float* __restrict__ x,
    const unsigned short* __restrict__ wxr,
    const unsigned short* __restrict__ whr,
    const float* __restrict__ bias,
    const unsigned short* __restrict__ h_prev,
    unsigned short* __restrict__ h_out,
    float* __restrict__ c_io,
    int t, int first)
{
    __shared__ char sh[5 * 68 * 128];          // swizzled bf16 h tile [ky][px][64ch]
    __shared__ unsigned short sxp[5 * 64 * 40]; // packed x taps [ky][px][k(32 used of 40)]

    const int b = blockIdx.z, y = blockIdx.y, x0 = blockIdx.x * MT;
    const int tid = threadIdx.x;
    const int w = tid >> 6, l = tid & 63;
    const int m0 = l & 15, kq = l >> 4;

    // zero sxp (pad lanes must read 0)
    for (int e = tid; e < 1600; e += 256)
        *(uint4*)((char*)sxp + e * 16) = make_uint4(0, 0, 0, 0);

    // stage h tile (bf16, XOR-swizzled rows)
    if (!first) {
        for (int e = tid; e < 5 * 68 * 8; e += 256) {
            int ky = e / (68 * 8);
            int rem = e - ky * 68 * 8;
            int px = rem >> 3, cg = rem & 7;
            int yg = y + ky - 2, xg = x0 + px - 2;
            uint4 v = make_uint4(0, 0, 0, 0);
            if (yg >= 0 && yg < H_ && (unsigned)xg < W_)
                v = *(const uint4*)(h_prev + ((((size_t)(b * H_ + yg)) * W_ + xg) << 6) + cg * 8);
            int off = ((ky * 68 + px) * 128 + cg * 16) ^ ((px & 7) << 4);
            *(uint4*)(sh + off) = v;
        }
    }
    __syncthreads();

    // fill packed x taps: sxp[ky][p][kx*3+c] = x(y+ky-2, x0+p+kx-2, c)
    for (int e = tid; e < 5 * 64 * 15; e += 256) {
        int ky = e / 960;
        int rem = e - ky * 960;
        int p = rem / 15, q = rem - p * 15;
        int kx = q / 3, c = q - kx * 3;
        int yg = y + ky - 2, xg = x0 + p + kx - 2;
        float v = 0.f;
        if (yg >= 0 && yg < H_ && (unsigned)xg < W_)
            v = x[(((size_t)((b * T_ + t) * H_ + yg)) * W_ + xg) * 3 + c];
        sxp[(ky * 64 + p) * 40 + q] = f2bf(v);
    }
    __syncthreads();

    f32x4 acc[4][4]; // [row-frag][gate]
#pragma unroll
    for (int rf = 0; rf < 4; ++rf)
#pragma unroll
        for (int g = 0; g < 4; ++g) acc[rf][g] = (f32x4){0.f, 0.f, 0.f, 0.f};

    // x-conv: 5 K-steps (one per ky)
    for (int ky = 0; ky < 5; ++ky) {
        bf16x8 a[4], bb[4];
#pragma unroll
        for (int rf = 0; rf < 4; ++rf) {
            int px = rf * 16 + m0;
            a[rf] = *(const bf16x8*)&sxp[(ky * 64 + px) * 40 + kq * 8];
        }
#pragma unroll
        for (int g = 0; g < 4; ++g)
            bb[g] = *(const bf16x8*)(wxr + ((size_t)((ky * 16 + g * 4 + w) * 64 + l)) * 8);
#pragma unroll
        for (int rf = 0; rf < 4; ++rf)
#pragma unroll
            for (int g = 0; g < 4; ++g)
                acc[rf][g] = __builtin_amdgcn_mfma_f32_16x16x32_bf16(a[rf], bb[g], acc[rf][g], 0, 0, 0);
    }

    // h-conv: 50 K-steps (25 taps x 2 channel-halves)
    if (!first) {
        for (int tap = 0; tap < 25; ++tap) {
            const int ky = tap / 5, kx = tap - ky * 5;
#pragma unroll
            for (int ch = 0; ch < 2; ++ch) {
                bf16x8 a[4], bb[4];
#pragma unroll
                for (int rf = 0; rf < 4; ++rf) {
                    int px = rf * 16 + m0 + kx;
                    int off = ((ky * 68 + px) * 128 + ch * 64 + kq * 16) ^ ((px & 7) << 4);
                    a[rf] = *(const bf16x8*)(sh + off);
                }
#pragma unroll
                for (int g = 0; g < 4; ++g)
                    bb[g] = *(const bf16x8*)(whr + ((size_t)(((tap * 2 + ch) * 16 + g * 4 + w) * 64 + l)) * 8);
#pragma unroll
                for (int rf = 0; rf < 4; ++rf)
#pragma unroll
                    for (int g = 0; g < 4; ++g)
                        acc[rf][g] = __builtin_amdgcn_mfma_f32_16x16x32_bf16(a[rf], bb[g], acc[rf][g], 0, 0, 0);
            }
        }
    }

    // epilogue: gate combine (all 4 gates wave-local)
    const int f = (w << 4) + m0;
    const float bi0 = bias[f], bi1 = bias[64 + f], bi2 = bias[128 + f], bi3 = bias[192 + f];
#pragma unroll
    for (int rf = 0; rf < 4; ++rf) {
#pragma unroll
        for (int r = 0; r < 4; ++r) {
            int px = x0 + rf * 16 + kq * 4 + r;
            size_t idx = ((((size_t)(b * H_ + y)) * W_ + px) << 6) + f;
            float zi = acc[rf][0][r] + bi0;
            float zf = acc[rf][1][r] + bi1;
            float zc = acc[rf][2][r] + bi2;
            float zo = acc[rf][3][r] + bi3;
            float cp = first ? 0.f : c_io[idx];
            float cn = hs_(zf) * cp + hs_(zi) * tanhf(zc);
            float hn = hs_(zo) * tanhf(cn);
            c_io[idx] = cn;
            h_out[idx] = f2bf(hn);
        }
    }
}

// -------- BatchNorm (inference), bf16 in -> f32 out --------
__global__ void bn_k(const unsigned short* __restrict__ in, float* __restrict__ out,
                     const float* __restrict__ gamma, const float* __restrict__ beta,
                     const float* __restrict__ mean, const float* __restrict__ var, int n) {
    for (int i = blockIdx.x * blockDim.x + threadIdx.x; i < n; i += gridDim.x * blockDim.x) {
        int c = i & 63;
        float s = rsqrtf(var[c] + 1e-3f) * gamma[c];
        out[i] = (bf2f(in[i]) - mean[c]) * s + beta[c];
    }
}

// -------- generic direct conv, LDS-tiled, ReLU --------
template <int KH, int KW, int CIN, int COUT, int CC, int TW>
__global__ __launch_bounds__(256) void conv2d_k(
    const float* __restrict__ in, const float* __restrict__ wgt,
    const float* __restrict__ bias, float* __restrict__ out)
{
    constexpr int PG = 256 / COUT;
    constexpr int PXT = TW / PG;
    constexpr int TC = TW + KW - 1;
    constexpr int PADX = KW / 2, PADY = KH / 2;
    __shared__ float s[KH][TC][CC + 1];

    const int b = blockIdx.z, y = blockIdx.y, x0 = blockIdx.x * TW;
    const int tid = threadIdx.x;
    const int cout = tid % COUT;
    const int pg = tid / COUT;
    const int p0 = pg * PXT;

    float acc[PXT];
#pragma unroll
    for (int p = 0; p < PXT; ++p) acc[p] = 0.f;

    for (int c0 = 0; c0 < CIN; c0 += CC) {
        __syncthreads();
        for (int e = tid; e < KH * TC * CC; e += 256) {
            int r = e / (TC * CC);
            int rem = e % (TC * CC);
            int cc = rem / CC, ch = rem % CC;
            int yg = y + r - PADY, xg = x0 + cc - PADX;
            float v = 0.f;
            if (yg >= 0 && yg < H_ && xg >= 0 && xg < W_)
                v = in[((b * H_ + yg) * W_ + xg) * CIN + c0 + ch];
            s[r][cc][ch] = v;
        }
        __syncthreads();
        for (int ky = 0; ky < KH; ++ky) {
#pragma unroll
            for (int kx = 0; kx < KW; ++kx) {
                for (int c = 0; c < CC; ++c) {
                    float w = wgt[(((ky * KW + kx) * CIN) + c0 + c) * COUT + cout];
#pragma unroll
                    for (int p = 0; p < PXT; ++p)
                        acc[p] = fmaf(s[ky][p0 + p + kx][c], w, acc[p]);
                }
            }
        }
    }

    float bv = bias[cout];
#pragma unroll
    for (int p = 0; p < PXT; ++p) {
        float v = fmaxf(acc[p] + bv, 0.f);
        out[((b * H_ + y) * W_ + x0 + p0 + p) * COUT + cout] = v;
    }
}

// -------- conv5: 3x3, 64 -> 3, sigmoid --------
__global__ __launch_bounds__(256) void conv5_k(
    const float* __restrict__ in, const float* __restrict__ wgt,
    const float* __restrict__ bias, float* __restrict__ out)
{
    constexpr int CC = 16;
    __shared__ float s[3][W_ + 2][CC + 1];
    const int b = blockIdx.z, y = blockIdx.y;
    const int tid = threadIdx.x;

    float acc[3] = {0.f, 0.f, 0.f};
    for (int c0 = 0; c0 < 64; c0 += CC) {
        __syncthreads();
        for (int e = tid; e < 3 * (W_ + 2) * CC; e += 256) {
            int r = e / ((W_ + 2) * CC);
            int rem = e % ((W_ + 2) * CC);
            int cc = rem / CC, ch = rem % CC;
            int yg = y + r - 1, xg = cc - 1;
            float v = 0.f;
            if (yg >= 0 && yg < H_ && xg >= 0 && xg < W_)
                v = in[((b * H_ + yg) * W_ + xg) * 64 + c0 + ch];
            s[r][cc][ch] = v;
        }
        __syncthreads();
        for (int ky = 0; ky < 3; ++ky) {
#pragma unroll
            for (int kx = 0; kx < 3; ++kx) {
                for (int c = 0; c < CC; ++c) {
                    const float* wp = &wgt[((ky * 3 + kx) * 64 + c0 + c) * 3];
                    float v = s[ky][tid + kx][c];
                    acc[0] = fmaf(v, wp[0], acc[0]);
                    acc[1] = fmaf(v, wp[1], acc[1]);
                    acc[2] = fmaf(v, wp[2], acc[2]);
                }
            }
        }
    }
#pragma unroll
    for (int j = 0; j < 3; ++j) {
        float v = acc[j] + bias[j];
        v = 1.f / (1.f + expf(-v));
        out[((b * H_ + y) * W_ + tid) * 3 + j] = v;
    }
}

extern "C" void kernel_launch(void* const* d_in, const int* in_sizes, int n_in,
                              void* d_out, int out_size, void* d_ws, size_t ws_size,
                              hipStream_t stream) {
    const float* x     = (const float*)d_in[0];
    const float* Wx    = (const float*)d_in[1];
    const float* Wh    = (const float*)d_in[2];
    const float* bl    = (const float*)d_in[3];
    const float* gamma = (const float*)d_in[4];
    const float* beta  = (const float*)d_in[5];
    const float* mmean = (const float*)d_in[6];
    const float* mvar  = (const float*)d_in[7];
    const float* W1 = (const float*)d_in[8];
    const float* b1 = (const float*)d_in[9];
    const float* W2 = (const float*)d_in[10];
    const float* b2 = (const float*)d_in[11];
    const float* W3 = (const float*)d_in[12];
    const float* b3 = (const float*)d_in[13];
    const float* W4 = (const float*)d_in[14];
    const float* b4 = (const float*)d_in[15];
    const float* W5 = (const float*)d_in[16];
    const float* b5 = (const float*)d_in[17];
    float* out = (float*)d_out;

    const size_t NHWF = (size_t)B_ * H_ * W_ * 64;
    char* p = (char*)d_ws;
    float* c_buf = (float*)p;                 p += NHWF * 4;  // c; later bnout; later conv4out
    unsigned short* hA = (unsigned short*)p;  p += NHWF * 2;  // h ping; later conv1out (f32 16ch)
    unsigned short* hB = (unsigned short*)p;  p += NHWF * 2;  // h pong; later conv2out (f32 32ch)
    float* t3 = (float*)p;                    p += NHWF * 4;  // conv3out
    unsigned short* whr = (unsigned short*)p; p += (size_t)25 * 2 * 16 * 64 * 8 * 2;
    unsigned short* wxr = (unsigned short*)p;

    repack_wh_mfma<<<(25 * 2 * 4 * 4 * 64 + 255) / 256, 256, 0, stream>>>(Wh, whr);
    repack_wx_mfma<<<(5 * 4 * 4 * 64 + 255) / 256, 256, 0, stream>>>(Wx, wxr);

    dim3 lgrid(W_ / MT, H_, B_);
    for (int t = 0; t < T_; ++t) {
        const unsigned short* hp = (t & 1) ? hA : hB;
        unsigned short* ho = (t & 1) ? hB : hA;
        lstm_mfma<<<lgrid, 256, 0, stream>>>(x, wxr, whr, bl, hp, ho, c_buf, t, t == 0 ? 1 : 0);
    }
    // final h in hB

    bn_k<<<2048, 256, 0, stream>>>(hB, c_buf, gamma, beta, mmean, mvar, (int)NHWF);

    float* o1 = (float*)hA;
    float* o2 = (float*)hB;
    conv2d_k<9, 9, 64, 16, 16, 64><<<dim3(W_ / 64, H_, B_), 256, 0, stream>>>(c_buf, W1, b1, o1);
    conv2d_k<5, 5, 16, 32, 16, 32><<<dim3(W_ / 32, H_, B_), 256, 0, stream>>>(o1, W2, b2, o2);
    conv2d_k<3, 3, 32, 64, 32, 16><<<dim3(W_ / 16, H_, B_), 256, 0, stream>>>(o2, W3, b3, t3);
    conv2d_k<3, 3, 64, 64, 32, 16><<<dim3(W_ / 16, H_, B_), 256, 0, stream>>>(t3, W4, b4, c_buf);
    conv5_k<<<dim3(1, H_, B_), 256, 0, stream>>>(c_buf, W5, b5, out);
}

// Round 3
// 1881.718 us; speedup vs baseline: 8.1991x; 1.6306x over previous
//
#include <hip/hip_runtime.h>
#include <math.h>

#define B_ 4
#define T_ 10
#define H_ 144
#define W_ 256
#define F_ 64

typedef __attribute__((ext_vector_type(8))) __bf16 bf16x8;
typedef __attribute__((ext_vector_type(4))) float f32x4;

static __device__ __forceinline__ float hs_(float x) {
    return fminf(fmaxf(fmaf(x, 0.2f, 0.5f), 0.f), 1.f);
}
static __device__ __forceinline__ unsigned short f2bf(float f) {
    unsigned u = __builtin_bit_cast(unsigned, f);
    u += 0x7fff + ((u >> 16) & 1);
    return (unsigned short)(u >> 16);
}
static __device__ __forceinline__ float bf2f(unsigned short s) {
    unsigned u = ((unsigned)s) << 16;
    return __builtin_bit_cast(float, u);
}

// ---- repack Wh [5][5][64][256] -> [25][2][4 gate][4 wf][64 lane][8] bf16 ----
__global__ void repack_wh_mfma(const float* __restrict__ w, unsigned short* __restrict__ o) {
    int idx = blockIdx.x * 256 + threadIdx.x;
    if (idx >= 25 * 2 * 4 * 4 * 64) return;
    int l = idx & 63;
    int wf = (idx >> 6) & 3;
    int g = (idx >> 8) & 3;
    int ch = (idx >> 10) & 1;
    int tap = idx >> 11;
    int n = g * 64 + wf * 16 + (l & 15);
    unsigned short* dst = o + (size_t)idx * 8;
#pragma unroll
    for (int j = 0; j < 8; ++j) {
        int c = ch * 32 + (l >> 4) * 8 + j;
        dst[j] = f2bf(w[((size_t)(tap * 64 + c)) * 256 + n]);
    }
}

// ---- repack Wx [5][5][3][256] -> [5 ky][4 gate][4 wf][64 lane][8] bf16 ----
__global__ void repack_wx_mfma(const float* __restrict__ w, unsigned short* __restrict__ o) {
    int idx = blockIdx.x * 256 + threadIdx.x;
    if (idx >= 5 * 4 * 4 * 64) return;
    int l = idx & 63;
    int wf = (idx >> 6) & 3;
    int g = (idx >> 8) & 3;
    int ky = idx >> 10;
    int n = g * 64 + wf * 16 + (l & 15);
    unsigned short* dst = o + (size_t)idx * 8;
#pragma unroll
    for (int j = 0; j < 8; ++j) {
        int k = (l >> 4) * 8 + j;
        unsigned short v = 0;
        if (k < 15) {
            int kx = k / 3, c = k - kx * 3;
            v = f2bf(w[((size_t)((ky * 5 + kx) * 3 + c)) * 256 + n]);
        }
        dst[j] = v;
    }
}

// ---- generic conv weight repack: [taps][CIN][COUT] f32 -> [tap][2ch][NF][64][8] bf16 ----
__global__ void repack_conv(const float* __restrict__ w, unsigned short* __restrict__ o,
                            int taps, int cin, int cout) {
    int NF = cout >> 4;
    int total = taps * 2 * NF * 64;
    int idx = blockIdx.x * 256 + threadIdx.x;
    if (idx >= total) return;
    int l = idx & 63;
    int nf = (idx >> 6) % NF;
    int ch = ((idx >> 6) / NF) & 1;
    int tap = (idx >> 6) / NF / 2;
    int n = nf * 16 + (l & 15);
    unsigned short* dst = o + (size_t)idx * 8;
#pragma unroll
    for (int j = 0; j < 8; ++j) {
        int c = ch * 32 + (l >> 4) * 8 + j;
        dst[j] = (c < cin) ? f2bf(w[((size_t)(tap * cin + c)) * cout + n]) : (unsigned short)0;
    }
}

// ---- fused ConvLSTM step via bf16 MFMA ----
#define MT 64
__global__ __launch_bounds__(256) void lstm_mfma(
    const float* __restrict__ x,
    const unsigned short* __restrict__ wxr,
    const unsigned short* __restrict__ whr,
    const float* __restrict__ bias,
    const unsigned short* __restrict__ h_prev,
    unsigned short* __restrict__ h_out,
    float* __restrict__ c_io,
    int t, int first)
{
    __shared__ char sh[5 * 68 * 128];
    __shared__ unsigned short sxp[5 * 64 * 40];

    const int b = blockIdx.z, y = blockIdx.y, x0 = blockIdx.x * MT;
    const int tid = threadIdx.x;
    const int w = tid >> 6, l = tid & 63;
    const int m0 = l & 15, kq = l >> 4;

    for (int e = tid; e < 1600; e += 256)
        *(uint4*)((char*)sxp + e * 16) = make_uint4(0, 0, 0, 0);

    if (!first) {
        for (int e = tid; e < 5 * 68 * 8; e += 256) {
            int ky = e / (68 * 8);
            int rem = e - ky * 68 * 8;
            int px = rem >> 3, cg = rem & 7;
            int yg = y + ky - 2, xg = x0 + px - 2;
            uint4 v = make_uint4(0, 0, 0, 0);
            if (yg >= 0 && yg < H_ && (unsigned)xg < W_)
                v = *(const uint4*)(h_prev + ((((size_t)(b * H_ + yg)) * W_ + xg) << 6) + cg * 8);
            int off = ((ky * 68 + px) * 128 + cg * 16) ^ ((px & 7) << 4);
            *(uint4*)(sh + off) = v;
        }
    }
    __syncthreads();

    for (int e = tid; e < 5 * 64 * 15; e += 256) {
        int ky = e / 960;
        int rem = e - ky * 960;
        int p = rem / 15, q = rem - p * 15;
        int kx = q / 3, c = q - kx * 3;
        int yg = y + ky - 2, xg = x0 + p + kx - 2;
        float v = 0.f;
        if (yg >= 0 && yg < H_ && (unsigned)xg < W_)
            v = x[(((size_t)((b * T_ + t) * H_ + yg)) * W_ + xg) * 3 + c];
        sxp[(ky * 64 + p) * 40 + q] = f2bf(v);
    }
    __syncthreads();

    f32x4 acc[4][4];
#pragma unroll
    for (int rf = 0; rf < 4; ++rf)
#pragma unroll
        for (int g = 0; g < 4; ++g) acc[rf][g] = (f32x4){0.f, 0.f, 0.f, 0.f};

    for (int ky = 0; ky < 5; ++ky) {
        bf16x8 a[4], bb[4];
#pragma unroll
        for (int rf = 0; rf < 4; ++rf) {
            int px = rf * 16 + m0;
            a[rf] = *(const bf16x8*)&sxp[(ky * 64 + px) * 40 + kq * 8];
        }
#pragma unroll
        for (int g = 0; g < 4; ++g)
            bb[g] = *(const bf16x8*)(wxr + ((size_t)((ky * 16 + g * 4 + w) * 64 + l)) * 8);
#pragma unroll
        for (int rf = 0; rf < 4; ++rf)
#pragma unroll
            for (int g = 0; g < 4; ++g)
                acc[rf][g] = __builtin_amdgcn_mfma_f32_16x16x32_bf16(a[rf], bb[g], acc[rf][g], 0, 0, 0);
    }

    if (!first) {
        for (int tap = 0; tap < 25; ++tap) {
            const int ky = tap / 5, kx = tap - ky * 5;
#pragma unroll
            for (int ch = 0; ch < 2; ++ch) {
                bf16x8 a[4], bb[4];
#pragma unroll
                for (int rf = 0; rf < 4; ++rf) {
                    int px = rf * 16 + m0 + kx;
                    int off = ((ky * 68 + px) * 128 + ch * 64 + kq * 16) ^ ((px & 7) << 4);
                    a[rf] = *(const bf16x8*)(sh + off);
                }
#pragma unroll
                for (int g = 0; g < 4; ++g)
                    bb[g] = *(const bf16x8*)(whr + ((size_t)(((tap * 2 + ch) * 16 + g * 4 + w) * 64 + l)) * 8);
#pragma unroll
                for (int rf = 0; rf < 4; ++rf)
#pragma unroll
                    for (int g = 0; g < 4; ++g)
                        acc[rf][g] = __builtin_amdgcn_mfma_f32_16x16x32_bf16(a[rf], bb[g], acc[rf][g], 0, 0, 0);
            }
        }
    }

    const int f = (w << 4) + m0;
    const float bi0 = bias[f], bi1 = bias[64 + f], bi2 = bias[128 + f], bi3 = bias[192 + f];
#pragma unroll
    for (int rf = 0; rf < 4; ++rf) {
#pragma unroll
        for (int r = 0; r < 4; ++r) {
            int px = x0 + rf * 16 + kq * 4 + r;
            size_t idx = ((((size_t)(b * H_ + y)) * W_ + px) << 6) + f;
            float zi = acc[rf][0][r] + bi0;
            float zf = acc[rf][1][r] + bi1;
            float zc = acc[rf][2][r] + bi2;
            float zo = acc[rf][3][r] + bi3;
            float cp = first ? 0.f : c_io[idx];
            float cn = hs_(zf) * cp + hs_(zi) * tanhf(zc);
            float hn = hs_(zo) * tanhf(cn);
            c_io[idx] = cn;
            h_out[idx] = f2bf(hn);
        }
    }
}

// -------- BatchNorm (inference), bf16 in -> bf16 out --------
__global__ void bn_k(const unsigned short* __restrict__ in, unsigned short* __restrict__ out,
                     const float* __restrict__ gamma, const float* __restrict__ beta,
                     const float* __restrict__ mean, const float* __restrict__ var, int n) {
    for (int i = blockIdx.x * blockDim.x + threadIdx.x; i < n; i += gridDim.x * blockDim.x) {
        int c = i & 63;
        float s = rsqrtf(var[c] + 1e-3f) * gamma[c];
        out[i] = f2bf((bf2f(in[i]) - mean[c]) * s + beta[c]);
    }
}

// ---- generic MFMA conv: bf16 in [B,H,W,CIN] -> ReLU -> bf16 out [B,H,W,COUT] ----
// grid (W/64, H, B), block 256; wave w owns px [16w,16w+16) x all COUT
template <int KH, int KW, int CIN, int COUT, int KYB>
__global__ __launch_bounds__(256) void conv_mfma(
    const unsigned short* __restrict__ in, const unsigned short* __restrict__ wr,
    const float* __restrict__ bias, unsigned short* __restrict__ out)
{
    constexpr int TC = 64 + KW - 1;
    constexpr int PADX = KW / 2, PADY = KH / 2;
    constexpr int NF = COUT / 16;
    constexpr int CHN = (CIN + 31) / 32;
    constexpr int NKG = KH / KYB;
    __shared__ char sh[KYB * TC * 128];

    const int b = blockIdx.z, y = blockIdx.y, x0 = blockIdx.x * 64;
    const int tid = threadIdx.x;
    const int w = tid >> 6, l = tid & 63;
    const int m0 = l & 15, kq = l >> 4;

    f32x4 acc[NF];
#pragma unroll
    for (int nf = 0; nf < NF; ++nf) acc[nf] = (f32x4){0.f, 0.f, 0.f, 0.f};

    for (int kg = 0; kg < NKG; ++kg) {
        __syncthreads();
        for (int e = tid; e < KYB * TC * 8; e += 256) {
            int kyl = e / (TC * 8);
            int rem = e - kyl * TC * 8;
            int px = rem >> 3, cg = rem & 7;
            int ky = kg * KYB + kyl;
            int yg = y + ky - PADY, xg = x0 + px - PADX;
            int c0 = cg * 8;
            uint4 v = make_uint4(0, 0, 0, 0);
            if (yg >= 0 && yg < H_ && (unsigned)xg < W_ && c0 < CIN)
                v = *(const uint4*)(in + ((size_t)((b * H_ + yg) * W_) + xg) * CIN + c0);
            int off = ((kyl * TC + px) * 128 + cg * 16) ^ ((px & 7) << 4);
            *(uint4*)(sh + off) = v;
        }
        __syncthreads();

        for (int kyl = 0; kyl < KYB; ++kyl) {
            int ky = kg * KYB + kyl;
#pragma unroll
            for (int kx = 0; kx < KW; ++kx) {
#pragma unroll
                for (int ch = 0; ch < CHN; ++ch) {
                    int px = w * 16 + m0 + kx;
                    int off = ((kyl * TC + px) * 128 + ch * 64 + kq * 16) ^ ((px & 7) << 4);
                    bf16x8 a = *(const bf16x8*)(sh + off);
                    int tap = ky * KW + kx;
                    const unsigned short* wp = wr + ((size_t)(((tap * 2 + ch) * NF) * 64 + l)) * 8;
#pragma unroll
                    for (int nf = 0; nf < NF; ++nf) {
                        bf16x8 bb = *(const bf16x8*)(wp + nf * 512);
                        acc[nf] = __builtin_amdgcn_mfma_f32_16x16x32_bf16(a, bb, acc[nf], 0, 0, 0);
                    }
                }
            }
        }
    }

#pragma unroll
    for (int nf = 0; nf < NF; ++nf) {
        int cout = nf * 16 + m0;
        float bv = bias[cout];
#pragma unroll
        for (int r = 0; r < 4; ++r) {
            int px = x0 + w * 16 + kq * 4 + r;
            float v = fmaxf(acc[nf][r] + bv, 0.f);
            out[((size_t)((b * H_ + y) * W_) + px) * COUT + cout] = f2bf(v);
        }
    }
}

// -------- conv5: 3x3, 64 -> 3, sigmoid; bf16 in, f32 out --------
__global__ __launch_bounds__(256) void conv5_k(
    const unsigned short* __restrict__ in, const float* __restrict__ wgt,
    const float* __restrict__ bias, float* __restrict__ out)
{
    constexpr int CC = 16;
    __shared__ float s[3][W_ + 2][CC + 1];
    const int b = blockIdx.z, y = blockIdx.y;
    const int tid = threadIdx.x;

    float acc[3] = {0.f, 0.f, 0.f};
    for (int c0 = 0; c0 < 64; c0 += CC) {
        __syncthreads();
        for (int e = tid; e < 3 * (W_ + 2) * CC; e += 256) {
            int r = e / ((W_ + 2) * CC);
            int rem = e % ((W_ + 2) * CC);
            int cc = rem / CC, ch = rem % CC;
            int yg = y + r - 1, xg = cc - 1;
            float v = 0.f;
            if (yg >= 0 && yg < H_ && xg >= 0 && xg < W_)
                v = bf2f(in[((b * H_ + yg) * W_ + xg) * 64 + c0 + ch]);
            s[r][cc][ch] = v;
        }
        __syncthreads();
        for (int ky = 0; ky < 3; ++ky) {
#pragma unroll
            for (int kx = 0; kx < 3; ++kx) {
                for (int c = 0; c < CC; ++c) {
                    const float* wp = &wgt[((ky * 3 + kx) * 64 + c0 + c) * 3];
                    float v = s[ky][tid + kx][c];
                    acc[0] = fmaf(v, wp[0], acc[0]);
                    acc[1] = fmaf(v, wp[1], acc[1]);
                    acc[2] = fmaf(v, wp[2], acc[2]);
                }
            }
        }
    }
#pragma unroll
    for (int j = 0; j < 3; ++j) {
        float v = acc[j] + bias[j];
        v = 1.f / (1.f + expf(-v));
        out[((b * H_ + y) * W_ + tid) * 3 + j] = v;
    }
}

extern "C" void kernel_launch(void* const* d_in, const int* in_sizes, int n_in,
                              void* d_out, int out_size, void* d_ws, size_t ws_size,
                              hipStream_t stream) {
    const float* x     = (const float*)d_in[0];
    const float* Wx    = (const float*)d_in[1];
    const float* Wh    = (const float*)d_in[2];
    const float* bl    = (const float*)d_in[3];
    const float* gamma = (const float*)d_in[4];
    const float* beta  = (const float*)d_in[5];
    const float* mmean = (const float*)d_in[6];
    const float* mvar  = (const float*)d_in[7];
    const float* W1 = (const float*)d_in[8];
    const float* b1 = (const float*)d_in[9];
    const float* W2 = (const float*)d_in[10];
    const float* b2 = (const float*)d_in[11];
    const float* W3 = (const float*)d_in[12];
    const float* b3 = (const float*)d_in[13];
    const float* W4 = (const float*)d_in[14];
    const float* b4 = (const float*)d_in[15];
    const float* W5 = (const float*)d_in[16];
    const float* b5 = (const float*)d_in[17];
    float* out = (float*)d_out;

    const size_t NHWF = (size_t)B_ * H_ * W_ * 64;  // 9.44M
    char* p = (char*)d_ws;
    float* c_buf = (float*)p;                 p += NHWF * 4;  // c state; later o1/o2
    unsigned short* hA = (unsigned short*)p;  p += NHWF * 2;  // h ping; later BN out; later o4
    unsigned short* hB = (unsigned short*)p;  p += NHWF * 2;  // h pong (final h); later o3
    unsigned short* whr = (unsigned short*)p; p += (size_t)25 * 2 * 16 * 64 * 8 * 2;
    unsigned short* wxr = (unsigned short*)p; p += (size_t)5 * 16 * 64 * 8 * 2;
    unsigned short* w1r = (unsigned short*)p; p += (size_t)81 * 2 * 1 * 512 * 2;
    unsigned short* w2r = (unsigned short*)p; p += (size_t)25 * 2 * 2 * 512 * 2;
    unsigned short* w3r = (unsigned short*)p; p += (size_t)9 * 2 * 4 * 512 * 2;
    unsigned short* w4r = (unsigned short*)p; p += (size_t)9 * 2 * 4 * 512 * 2;

    repack_wh_mfma<<<(25 * 2 * 4 * 4 * 64 + 255) / 256, 256, 0, stream>>>(Wh, whr);
    repack_wx_mfma<<<(5 * 4 * 4 * 64 + 255) / 256, 256, 0, stream>>>(Wx, wxr);
    repack_conv<<<(81 * 2 * 1 * 64 + 255) / 256, 256, 0, stream>>>(W1, w1r, 81, 64, 16);
    repack_conv<<<(25 * 2 * 2 * 64 + 255) / 256, 256, 0, stream>>>(W2, w2r, 25, 16, 32);
    repack_conv<<<(9 * 2 * 4 * 64 + 255) / 256, 256, 0, stream>>>(W3, w3r, 9, 32, 64);
    repack_conv<<<(9 * 2 * 4 * 64 + 255) / 256, 256, 0, stream>>>(W4, w4r, 9, 64, 64);

    dim3 lgrid(W_ / MT, H_, B_);
    for (int t = 0; t < T_; ++t) {
        const unsigned short* hp = (t & 1) ? hA : hB;
        unsigned short* ho = (t & 1) ? hB : hA;
        lstm_mfma<<<lgrid, 256, 0, stream>>>(x, wxr, whr, bl, hp, ho, c_buf, t, t == 0 ? 1 : 0);
    }
    // final h in hB; hA free after BN consumes nothing from it (BN: hB -> hA)

    unsigned short* bnb = hA;
    bn_k<<<2048, 256, 0, stream>>>(hB, bnb, gamma, beta, mmean, mvar, (int)NHWF);

    // c no longer needed -> reuse c_buf region for o1 (bf16 16ch) and o2 (bf16 32ch)
    unsigned short* o1 = (unsigned short*)c_buf;
    unsigned short* o2 = o1 + NHWF / 4;            // after 4.7MB of o1 (NHW*16 elems)
    unsigned short* o3 = hB;                        // hB free after conv1 reads? (BN read hB; conv1 reads bnb=hA)
    unsigned short* o4 = hA;                        // hA free after conv2 (conv1 read it)

    dim3 cgrid(W_ / 64, H_, B_);
    conv_mfma<9, 9, 64, 16, 3><<<cgrid, 256, 0, stream>>>(bnb, w1r, b1, o1);
    conv_mfma<5, 5, 16, 32, 5><<<cgrid, 256, 0, stream>>>(o1, w2r, b2, o2);
    conv_mfma<3, 3, 32, 64, 3><<<cgrid, 256, 0, stream>>>(o2, w3r, b3, o3);
    conv_mfma<3, 3, 64, 64, 3><<<cgrid, 256, 0, stream>>>(o3, w4r, b4, o4);
    conv5_k<<<dim3(1, H_, B_), 256, 0, stream>>>(o4, W5, b5, out);
}

// Round 4
// 1486.814 us; speedup vs baseline: 10.3768x; 1.2656x over previous
//
#include <hip/hip_runtime.h>
#include <math.h>

#define B_ 4
#define T_ 10
#define H_ 144
#define W_ 256
#define F_ 64

typedef __attribute__((ext_vector_type(8))) __bf16 bf16x8;
typedef __attribute__((ext_vector_type(4))) float f32x4;

static __device__ __forceinline__ float hs_(float x) {
    return fminf(fmaxf(fmaf(x, 0.2f, 0.5f), 0.f), 1.f);
}
static __device__ __forceinline__ unsigned short f2bf(float f) {
    unsigned u = __builtin_bit_cast(unsigned, f);
    u += 0x7fff + ((u >> 16) & 1);
    return (unsigned short)(u >> 16);
}
static __device__ __forceinline__ float bf2f(unsigned short s) {
    unsigned u = ((unsigned)s) << 16;
    return __builtin_bit_cast(float, u);
}

// ---- repack Wh [5][5][64][256] -> [25][2][4 gate][4 wf][64 lane][8] bf16 ----
__global__ void repack_wh_mfma(const float* __restrict__ w, unsigned short* __restrict__ o) {
    int idx = blockIdx.x * 256 + threadIdx.x;
    if (idx >= 25 * 2 * 4 * 4 * 64) return;
    int l = idx & 63;
    int wf = (idx >> 6) & 3;
    int g = (idx >> 8) & 3;
    int ch = (idx >> 10) & 1;
    int tap = idx >> 11;
    int n = g * 64 + wf * 16 + (l & 15);
    unsigned short* dst = o + (size_t)idx * 8;
#pragma unroll
    for (int j = 0; j < 8; ++j) {
        int c = ch * 32 + (l >> 4) * 8 + j;
        dst[j] = f2bf(w[((size_t)(tap * 64 + c)) * 256 + n]);
    }
}

// ---- repack Wx [5][5][3][256] -> [5 ky][4 gate][4 wf][64 lane][8] bf16 ----
__global__ void repack_wx_mfma(const float* __restrict__ w, unsigned short* __restrict__ o) {
    int idx = blockIdx.x * 256 + threadIdx.x;
    if (idx >= 5 * 4 * 4 * 64) return;
    int l = idx & 63;
    int wf = (idx >> 6) & 3;
    int g = (idx >> 8) & 3;
    int ky = idx >> 10;
    int n = g * 64 + wf * 16 + (l & 15);
    unsigned short* dst = o + (size_t)idx * 8;
#pragma unroll
    for (int j = 0; j < 8; ++j) {
        int k = (l >> 4) * 8 + j;
        unsigned short v = 0;
        if (k < 15) {
            int kx = k / 3, c = k - kx * 3;
            v = f2bf(w[((size_t)((ky * 5 + kx) * 3 + c)) * 256 + n]);
        }
        dst[j] = v;
    }
}

// ---- generic conv weight repack: [taps][CIN][COUT] f32 -> [tap][2ch][NF][64][8] bf16 ----
__global__ void repack_conv(const float* __restrict__ w, unsigned short* __restrict__ o,
                            int taps, int cin, int cout) {
    int NF = cout >> 4;
    int total = taps * 2 * NF * 64;
    int idx = blockIdx.x * 256 + threadIdx.x;
    if (idx >= total) return;
    int l = idx & 63;
    int nf = (idx >> 6) % NF;
    int ch = ((idx >> 6) / NF) & 1;
    int tap = (idx >> 6) / NF / 2;
    int n = nf * 16 + (l & 15);
    unsigned short* dst = o + (size_t)idx * 8;
#pragma unroll
    for (int j = 0; j < 8; ++j) {
        int c = ch * 32 + (l >> 4) * 8 + j;
        dst[j] = (c < cin) ? f2bf(w[((size_t)(tap * cin + c)) * cout + n]) : (unsigned short)0;
    }
}

// ---- fused ConvLSTM step via bf16 MFMA, 3 blocks/CU, pipelined K-loop ----
#define MT 64
__global__ __launch_bounds__(256, 3) void lstm_mfma(
    const float* __restrict__ x,
    const unsigned short* __restrict__ wxr,
    const unsigned short* __restrict__ whr,
    const float* __restrict__ bias,
    const unsigned short* __restrict__ h_prev,
    unsigned short* __restrict__ h_out,
    float* __restrict__ c_io,
    int t, int first)
{
    __shared__ char sh[5 * 68 * 128];           // swizzled bf16 h tile [ky][px][64ch] = 43520 B
    __shared__ unsigned short sxr[5 * 72 * 4];  // raw bf16 x tile [ky][px][c(4)] = 2880 B

    const int b = blockIdx.z, y = blockIdx.y, x0 = blockIdx.x * MT;
    const int tid = threadIdx.x;
    const int w = tid >> 6, l = tid & 63;
    const int m0 = l & 15, kq = l >> 4;

    // per-thread k -> (kx*4+c) table for x A-frag gathers (invalid -> c=3 zero slot)
    int dj[8];
#pragma unroll
    for (int j = 0; j < 8; ++j) {
        int k = kq * 8 + j;
        int kx = k / 3, c = k - kx * 3;
        dj[j] = (k < 15) ? kx * 4 + c : 3;
    }

    // zero the c=3 column (read by pad lanes)
    for (int e = tid; e < 5 * 68; e += 256) {
        int ky = e / 68, px = e - ky * 68;
        sxr[(ky * 72 + px) * 4 + 3] = 0;
    }
    // stage raw x tile
    for (int e = tid; e < 5 * 68 * 3; e += 256) {
        int ky = e / 204;
        int rem = e - ky * 204;
        int px = rem / 3, c = rem - px * 3;
        int yg = y + ky - 2, xg = x0 + px - 2;
        float v = 0.f;
        if (yg >= 0 && yg < H_ && (unsigned)xg < W_)
            v = x[(((size_t)((b * T_ + t) * H_ + yg)) * W_ + xg) * 3 + c];
        sxr[(ky * 72 + px) * 4 + c] = f2bf(v);
    }
    // stage h tile (bf16, XOR-swizzled rows)
    if (!first) {
        for (int e = tid; e < 5 * 68 * 8; e += 256) {
            int ky = e / (68 * 8);
            int rem = e - ky * 68 * 8;
            int px = rem >> 3, cg = rem & 7;
            int yg = y + ky - 2, xg = x0 + px - 2;
            uint4 v = make_uint4(0, 0, 0, 0);
            if (yg >= 0 && yg < H_ && (unsigned)xg < W_)
                v = *(const uint4*)(h_prev + ((((size_t)(b * H_ + yg)) * W_ + xg) << 6) + cg * 8);
            int off = ((ky * 68 + px) * 128 + cg * 16) ^ ((px & 7) << 4);
            *(uint4*)(sh + off) = v;
        }
    }
    __syncthreads();

    f32x4 acc[4][4];
#pragma unroll
    for (int rf = 0; rf < 4; ++rf)
#pragma unroll
        for (int g = 0; g < 4; ++g) acc[rf][g] = (f32x4){0.f, 0.f, 0.f, 0.f};

    // x-conv: 5 K-steps, A built from raw tile via scalar LDS gathers
    for (int ky = 0; ky < 5; ++ky) {
        bf16x8 a[4], bb[4];
#pragma unroll
        for (int rf = 0; rf < 4; ++rf) {
            int base = (ky * 72 + rf * 16 + m0) * 4;
            union { bf16x8 v; unsigned short u[8]; } tt;
#pragma unroll
            for (int j = 0; j < 8; ++j) tt.u[j] = sxr[base + dj[j]];
            a[rf] = tt.v;
        }
#pragma unroll
        for (int g = 0; g < 4; ++g)
            bb[g] = *(const bf16x8*)(wxr + ((size_t)((ky * 16 + g * 4 + w) * 64 + l)) * 8);
#pragma unroll
        for (int rf = 0; rf < 4; ++rf)
#pragma unroll
            for (int g = 0; g < 4; ++g)
                acc[rf][g] = __builtin_amdgcn_mfma_f32_16x16x32_bf16(a[rf], bb[g], acc[rf][g], 0, 0, 0);
    }

    // h-conv: 50 K-steps, software-pipelined (alternating A0/B0, A1/B1)
    if (!first) {
        const unsigned short* wb = whr + (size_t)w * 512 + (size_t)l * 8;
#define LDA_(KY, KX, CH, A)                                                     \
        {                                                                       \
            _Pragma("unroll")                                                   \
            for (int rf = 0; rf < 4; ++rf) {                                    \
                int px = rf * 16 + m0 + (KX);                                   \
                int off = (((KY) * 68 + px) * 128 + (CH) * 64 + kq * 16) ^ ((px & 7) << 4); \
                (A)[rf] = *(const bf16x8*)(sh + off);                           \
            }                                                                   \
        }
#define LDB_(S, Bf)                                                             \
        {                                                                       \
            const unsigned short* wp = wb + (size_t)(S) * 8192;                 \
            _Pragma("unroll")                                                   \
            for (int g = 0; g < 4; ++g)                                         \
                (Bf)[g] = *(const bf16x8*)(wp + g * 2048);                      \
        }
#define MF_(A, Bf)                                                              \
        {                                                                       \
            _Pragma("unroll")                                                   \
            for (int rf = 0; rf < 4; ++rf)                                      \
                _Pragma("unroll")                                               \
                for (int g = 0; g < 4; ++g)                                     \
                    acc[rf][g] = __builtin_amdgcn_mfma_f32_16x16x32_bf16((A)[rf], (Bf)[g], acc[rf][g], 0, 0, 0); \
        }
        bf16x8 A0[4], B0[4], A1[4], B1[4];
        LDA_(0, 0, 0, A0);
        LDB_(0, B0);
        int ky = 0, kx = 0;
        for (int tap = 0; tap < 25; ++tap) {
            LDA_(ky, kx, 1, A1);
            LDB_(2 * tap + 1, B1);
            MF_(A0, B0);
            int nky = ky, nkx = kx + 1;
            if (nkx == 5) { nkx = 0; ++nky; }
            if (tap < 24) {
                LDA_(nky, nkx, 0, A0);
                LDB_(2 * tap + 2, B0);
            }
            MF_(A1, B1);
            ky = nky; kx = nkx;
        }
#undef LDA_
#undef LDB_
#undef MF_
    }

    const int f = (w << 4) + m0;
    const float bi0 = bias[f], bi1 = bias[64 + f], bi2 = bias[128 + f], bi3 = bias[192 + f];
#pragma unroll
    for (int rf = 0; rf < 4; ++rf) {
#pragma unroll
        for (int r = 0; r < 4; ++r) {
            int px = x0 + rf * 16 + kq * 4 + r;
            size_t idx = ((((size_t)(b * H_ + y)) * W_ + px) << 6) + f;
            float zi = acc[rf][0][r] + bi0;
            float zf = acc[rf][1][r] + bi1;
            float zc = acc[rf][2][r] + bi2;
            float zo = acc[rf][3][r] + bi3;
            float cp = first ? 0.f : c_io[idx];
            float cn = hs_(zf) * cp + hs_(zi) * tanhf(zc);
            float hn = hs_(zo) * tanhf(cn);
            c_io[idx] = cn;
            h_out[idx] = f2bf(hn);
        }
    }
}

// -------- BatchNorm (inference), bf16 in -> bf16 out --------
__global__ void bn_k(const unsigned short* __restrict__ in, unsigned short* __restrict__ out,
                     const float* __restrict__ gamma, const float* __restrict__ beta,
                     const float* __restrict__ mean, const float* __restrict__ var, int n) {
    for (int i = blockIdx.x * blockDim.x + threadIdx.x; i < n; i += gridDim.x * blockDim.x) {
        int c = i & 63;
        float s = rsqrtf(var[c] + 1e-3f) * gamma[c];
        out[i] = f2bf((bf2f(in[i]) - mean[c]) * s + beta[c]);
    }
}

// ---- generic MFMA conv: bf16 in [B,H,W,CIN] -> ReLU -> bf16 out [B,H,W,COUT] ----
template <int KH, int KW, int CIN, int COUT, int KYB>
__global__ __launch_bounds__(256) void conv_mfma(
    const unsigned short* __restrict__ in, const unsigned short* __restrict__ wr,
    const float* __restrict__ bias, unsigned short* __restrict__ out)
{
    constexpr int TC = 64 + KW - 1;
    constexpr int PADX = KW / 2, PADY = KH / 2;
    constexpr int NF = COUT / 16;
    constexpr int CHN = (CIN + 31) / 32;
    constexpr int NKG = KH / KYB;
    __shared__ char sh[KYB * TC * 128];

    const int b = blockIdx.z, y = blockIdx.y, x0 = blockIdx.x * 64;
    const int tid = threadIdx.x;
    const int w = tid >> 6, l = tid & 63;
    const int m0 = l & 15, kq = l >> 4;

    f32x4 acc[NF];
#pragma unroll
    for (int nf = 0; nf < NF; ++nf) acc[nf] = (f32x4){0.f, 0.f, 0.f, 0.f};

    for (int kg = 0; kg < NKG; ++kg) {
        __syncthreads();
        for (int e = tid; e < KYB * TC * 8; e += 256) {
            int kyl = e / (TC * 8);
            int rem = e - kyl * TC * 8;
            int px = rem >> 3, cg = rem & 7;
            int ky = kg * KYB + kyl;
            int yg = y + ky - PADY, xg = x0 + px - PADX;
            int c0 = cg * 8;
            uint4 v = make_uint4(0, 0, 0, 0);
            if (yg >= 0 && yg < H_ && (unsigned)xg < W_ && c0 < CIN)
                v = *(const uint4*)(in + ((size_t)((b * H_ + yg) * W_) + xg) * CIN + c0);
            int off = ((kyl * TC + px) * 128 + cg * 16) ^ ((px & 7) << 4);
            *(uint4*)(sh + off) = v;
        }
        __syncthreads();

        for (int kyl = 0; kyl < KYB; ++kyl) {
            int ky = kg * KYB + kyl;
#pragma unroll
            for (int kx = 0; kx < KW; ++kx) {
#pragma unroll
                for (int ch = 0; ch < CHN; ++ch) {
                    int px = w * 16 + m0 + kx;
                    int off = ((kyl * TC + px) * 128 + ch * 64 + kq * 16) ^ ((px & 7) << 4);
                    bf16x8 a = *(const bf16x8*)(sh + off);
                    int tap = ky * KW + kx;
                    const unsigned short* wp = wr + ((size_t)(((tap * 2 + ch) * NF) * 64 + l)) * 8;
#pragma unroll
                    for (int nf = 0; nf < NF; ++nf) {
                        bf16x8 bb = *(const bf16x8*)(wp + nf * 512);
                        acc[nf] = __builtin_amdgcn_mfma_f32_16x16x32_bf16(a, bb, acc[nf], 0, 0, 0);
                    }
                }
            }
        }
    }

#pragma unroll
    for (int nf = 0; nf < NF; ++nf) {
        int cout = nf * 16 + m0;
        float bv = bias[cout];
#pragma unroll
        for (int r = 0; r < 4; ++r) {
            int px = x0 + w * 16 + kq * 4 + r;
            float v = fmaxf(acc[nf][r] + bv, 0.f);
            out[((size_t)((b * H_ + y) * W_) + px) * COUT + cout] = f2bf(v);
        }
    }
}

// -------- conv5: 3x3, 64 -> 3, sigmoid; bf16 in, f32 out --------
__global__ __launch_bounds__(256) void conv5_k(
    const unsigned short* __restrict__ in, const float* __restrict__ wgt,
    const float* __restrict__ bias, float* __restrict__ out)
{
    constexpr int CC = 16;
    __shared__ float s[3][W_ + 2][CC + 1];
    const int b = blockIdx.z, y = blockIdx.y;
    const int tid = threadIdx.x;

    float acc[3] = {0.f, 0.f, 0.f};
    for (int c0 = 0; c0 < 64; c0 += CC) {
        __syncthreads();
        for (int e = tid; e < 3 * (W_ + 2) * CC; e += 256) {
            int r = e / ((W_ + 2) * CC);
            int rem = e % ((W_ + 2) * CC);
            int cc = rem / CC, ch = rem % CC;
            int yg = y + r - 1, xg = cc - 1;
            float v = 0.f;
            if (yg >= 0 && yg < H_ && xg >= 0 && xg < W_)
                v = bf2f(in[((b * H_ + yg) * W_ + xg) * 64 + c0 + ch]);
            s[r][cc][ch] = v;
        }
        __syncthreads();
        for (int ky = 0; ky < 3; ++ky) {
#pragma unroll
            for (int kx = 0; kx < 3; ++kx) {
                for (int c = 0; c < CC; ++c) {
                    const float* wp = &wgt[((ky * 3 + kx) * 64 + c0 + c) * 3];
                    float v = s[ky][tid + kx][c];
                    acc[0] = fmaf(v, wp[0], acc[0]);
                    acc[1] = fmaf(v, wp[1], acc[1]);
                    acc[2] = fmaf(v, wp[2], acc[2]);
                }
            }
        }
    }
#pragma unroll
    for (int j = 0; j < 3; ++j) {
        float v = acc[j] + bias[j];
        v = 1.f / (1.f + expf(-v));
        out[((b * H_ + y) * W_ + tid) * 3 + j] = v;
    }
}

extern "C" void kernel_launch(void* const* d_in, const int* in_sizes, int n_in,
                              void* d_out, int out_size, void* d_ws, size_t ws_size,
                              hipStream_t stream) {
    const float* x     = (const float*)d_in[0];
    const float* Wx    = (const float*)d_in[1];
    const float* Wh    = (const float*)d_in[2];
    const float* bl    = (const float*)d_in[3];
    const float* gamma = (const float*)d_in[4];
    const float* beta  = (const float*)d_in[5];
    const float* mmean = (const float*)d_in[6];
    const float* mvar  = (const float*)d_in[7];
    const float* W1 = (const float*)d_in[8];
    const float* b1 = (const float*)d_in[9];
    const float* W2 = (const float*)d_in[10];
    const float* b2 = (const float*)d_in[11];
    const float* W3 = (const float*)d_in[12];
    const float* b3 = (const float*)d_in[13];
    const float* W4 = (const float*)d_in[14];
    const float* b4 = (const float*)d_in[15];
    const float* W5 = (const float*)d_in[16];
    const float* b5 = (const float*)d_in[17];
    float* out = (float*)d_out;

    const size_t NHWF = (size_t)B_ * H_ * W_ * 64;  // 9.44M
    char* p = (char*)d_ws;
    float* c_buf = (float*)p;                 p += NHWF * 4;
    unsigned short* hA = (unsigned short*)p;  p += NHWF * 2;
    unsigned short* hB = (unsigned short*)p;  p += NHWF * 2;
    unsigned short* whr = (unsigned short*)p; p += (size_t)25 * 2 * 16 * 64 * 8 * 2;
    unsigned short* wxr = (unsigned short*)p; p += (size_t)5 * 16 * 64 * 8 * 2;
    unsigned short* w1r = (unsigned short*)p; p += (size_t)81 * 2 * 1 * 512 * 2;
    unsigned short* w2r = (unsigned short*)p; p += (size_t)25 * 2 * 2 * 512 * 2;
    unsigned short* w3r = (unsigned short*)p; p += (size_t)9 * 2 * 4 * 512 * 2;
    unsigned short* w4r = (unsigned short*)p; p += (size_t)9 * 2 * 4 * 512 * 2;

    repack_wh_mfma<<<(25 * 2 * 4 * 4 * 64 + 255) / 256, 256, 0, stream>>>(Wh, whr);
    repack_wx_mfma<<<(5 * 4 * 4 * 64 + 255) / 256, 256, 0, stream>>>(Wx, wxr);
    repack_conv<<<(81 * 2 * 1 * 64 + 255) / 256, 256, 0, stream>>>(W1, w1r, 81, 64, 16);
    repack_conv<<<(25 * 2 * 2 * 64 + 255) / 256, 256, 0, stream>>>(W2, w2r, 25, 16, 32);
    repack_conv<<<(9 * 2 * 4 * 64 + 255) / 256, 256, 0, stream>>>(W3, w3r, 9, 32, 64);
    repack_conv<<<(9 * 2 * 4 * 64 + 255) / 256, 256, 0, stream>>>(W4, w4r, 9, 64, 64);

    dim3 lgrid(W_ / MT, H_, B_);
    for (int t = 0; t < T_; ++t) {
        const unsigned short* hp = (t & 1) ? hA : hB;
        unsigned short* ho = (t & 1) ? hB : hA;
        lstm_mfma<<<lgrid, 256, 0, stream>>>(x, wxr, whr, bl, hp, ho, c_buf, t, t == 0 ? 1 : 0);
    }
    // final h in hB

    unsigned short* bnb = hA;
    bn_k<<<2048, 256, 0, stream>>>(hB, bnb, gamma, beta, mmean, mvar, (int)NHWF);

    unsigned short* o1 = (unsigned short*)c_buf;
    unsigned short* o2 = o1 + NHWF / 4;
    unsigned short* o3 = hB;
    unsigned short* o4 = hA;

    dim3 cgrid(W_ / 64, H_, B_);
    conv_mfma<9, 9, 64, 16, 3><<<cgrid, 256, 0, stream>>>(bnb, w1r, b1, o1);
    conv_mfma<5, 5, 16, 32, 5><<<cgrid, 256, 0, stream>>>(o1, w2r, b2, o2);
    conv_mfma<3, 3, 32, 64, 3><<<cgrid, 256, 0, stream>>>(o2, w3r, b3, o3);
    conv_mfma<3, 3, 64, 64, 3><<<cgrid, 256, 0, stream>>>(o3, w4r, b4, o4);
    conv5_k<<<dim3(1, H_, B_), 256, 0, stream>>>(o4, W5, b5, out);
}